// Round 6
// baseline (27.138 us; speedup 1.0000x reference)
//
#include <hip/hip_runtime.h>
#include <math.h>
#include <stdint.h>

#define Bsz 512
#define Nn 8192
#define Hh 5
#define Ss 10
#define KB 8            // batches per block
#define TILE 1024       // n per block
#define NT 256          // threads per block
#define TILES (Nn / TILE)

// LDS float layout (60 KB total, all regions WAVE-PRIVATE -> barrier-free):
//   [w*2560, w*2560+2560)   : wave w's region. Prologue: sW staging (2560 floats).
//                             Main loop: history double buffer (2 x 1280 floats).
//   [10240 + w*1280, +1280) : wave w's hw staging region.
#define LDS_FLOATS 15360

__device__ __forceinline__ float elu1(float v) {
    return v > 0.0f ? v : expm1f(v);
}

// One async global->LDS 16B/lane transfer: 64 lanes x 16 B = 1024 B = 256 floats.
// src is per-lane (pass base + lane*4 floats); dst is wave-uniform base.
__device__ __forceinline__ void gload16(const float* src, float* dst) {
    __builtin_amdgcn_global_load_lds(
        (const __attribute__((address_space(1))) uint32_t*)src,
        (__attribute__((address_space(3))) uint32_t*)dst, 16, 0, 0);
}

__global__ __launch_bounds__(NT, 2) void main_kernel(
    const float* __restrict__ x,         // [B,N]
    const float* __restrict__ history,   // [B,N,H]
    const float* __restrict__ state,     // [B,S]
    const float* __restrict__ hw,        // [N,H]
    const float* __restrict__ hb,        // [N]
    const float* __restrict__ sW,        // [N,S]
    const float* __restrict__ sb,        // [N]
    const float* __restrict__ ga,        // [N]
    const int*   __restrict__ sort_id,   // [B]
    const float* __restrict__ own_gain,  // [T]
    float* __restrict__ out)             // [B,N]
{
    __shared__ __align__(16) float lds[LDS_FLOATS];

    const int tid  = threadIdx.x;
    const int lane = tid & 63;
    const int wave = tid >> 6;
    const int tile  = blockIdx.x & (TILES - 1);
    const int chunk = blockIdx.x / TILES;
    const int n0 = tile * TILE;
    const int b0 = chunk * KB;
    const int nq = n0 + tid * 4;

    float* myreg = &lds[wave * 2560];          // sW staging, then hist dbuf
    float* myhw  = &lds[10240 + wave * 1280];  // hw staging

    // ---- per-n biases (dense, coalesced) ----
    float4 hbv = *reinterpret_cast<const float4*>(hb + nq);
    float4 sbv = *reinterpret_cast<const float4*>(sb + nq);
    float4 gav = *reinterpret_cast<const float4*>(ga + nq);

    // ---- batch gains, wave-parallel: 8 lane-groups x 8 lanes, taps j = r+8k ----
    float bgv[KB];
    {
        int grp = lane >> 3;
        int r   = lane & 7;
        int s   = sort_id[b0 + grp];
        int jmax = s < 100 ? s : 100;
        float acc = 0.0f;
        #pragma unroll
        for (int k = 0; k < 13; ++k) {
            int j = r + k * 8;
            if (j <= jmax) {
                float t = (float)j * (1.0f / 30.0f);
                acc = fmaf(expf(-0.5f * t * t), own_gain[s - j], acc);
            }
        }
        acc += __shfl_xor(acc, 1);
        acc += __shfl_xor(acc, 2);
        acc += __shfl_xor(acc, 4);
        #pragma unroll
        for (int g = 0; g < KB; ++g)
            bgv[g] = elu1(__shfl(acc, g * 8)) + 1.0f;
    }

    // ---- stage sW (10 loads) + hw (5 loads) into wave-private regions ----
    {
        const float* srcS = sW + (size_t)n0 * Ss + wave * 2560 + lane * 4;
        #pragma unroll
        for (int p = 0; p < 10; ++p) gload16(srcS + p * 256, myreg + p * 256);
        const float* srcA = hw + (size_t)n0 * Hh + wave * 1280 + lane * 4;
        #pragma unroll
        for (int p = 0; p < 5; ++p)  gload16(srcA + p * 256, myhw + p * 256);
    }
    asm volatile("s_waitcnt vmcnt(0)" ::: "memory");

    // ---- weights LDS -> registers (wave-private, no barrier needed) ----
    float wS[40], wA[20];
    #pragma unroll
    for (int i = 0; i < 10; ++i) {
        float4 t = *reinterpret_cast<float4*>(&myreg[lane * 40 + i * 4]);
        wS[i*4+0] = t.x; wS[i*4+1] = t.y; wS[i*4+2] = t.z; wS[i*4+3] = t.w;
    }
    #pragma unroll
    for (int i = 0; i < 5; ++i) {
        float4 t = *reinterpret_cast<float4*>(&myhw[lane * 20 + i * 4]);
        wA[i*4+0] = t.x; wA[i*4+1] = t.y; wA[i*4+2] = t.z; wA[i*4+3] = t.w;
    }
    asm volatile("" ::: "memory");   // weights consumed before region reuse below

    // ---- prologue prefetch: history[b0] -> buf0, x[b0] -> reg ----
    {
        const float* src = history + ((size_t)b0 * Nn + n0) * Hh + wave * 1280 + lane * 4;
        #pragma unroll
        for (int p = 0; p < 5; ++p) gload16(src + p * 256, myreg + p * 256);
    }
    float4 xv = *reinterpret_cast<const float4*>(x + (size_t)b0 * Nn + nq);

    #pragma unroll
    for (int kb = 0; kb < KB; ++kb) {
        const int b = b0 + kb;

        // own staged data landed (wave-private; no __syncthreads anywhere)
        asm volatile("s_waitcnt vmcnt(0)" ::: "memory");

        // prefetch next batch into the other half of this wave's region
        float4 xnext = xv;
        if (kb + 1 < KB) {
            const float* src = history + ((size_t)(b + 1) * Nn + n0) * Hh
                               + wave * 1280 + lane * 4;
            float* dst = myreg + ((kb + 1) & 1) * 1280;
            #pragma unroll
            for (int p = 0; p < 5; ++p) gload16(src + p * 256, dst + p * 256);
            xnext = *reinterpret_cast<const float4*>(x + (size_t)(b + 1) * Nn + nq);
        }

        // block-uniform state -> scalar loads
        float st[Ss];
        #pragma unroll
        for (int i = 0; i < Ss; ++i) st[i] = state[b * Ss + i];

        // history dot from this wave's current buffer
        const float* buf = myreg + (kb & 1) * 1280 + lane * 20;
        float hist[4] = {hbv.x, hbv.y, hbv.z, hbv.w};
        #pragma unroll
        for (int i = 0; i < 5; ++i) {
            float4 h = *reinterpret_cast<const float4*>(buf + i * 4);
            float hv4[4] = {h.x, h.y, h.z, h.w};
            #pragma unroll
            for (int j = 0; j < 4; ++j) {
                int f = i * 4 + j;                 // f = q*5 + h
                hist[f / Hh] = fmaf(hv4[j], wA[f], hist[f / Hh]);
            }
        }

        float sm[4] = {sbv.x, sbv.y, sbv.z, sbv.w};
        #pragma unroll
        for (int f = 0; f < 40; ++f)               // f = q*10 + s
            sm[f / Ss] = fmaf(st[f % Ss], wS[f], sm[f / Ss]);

        float xa[4]  = {xv.x, xv.y, xv.z, xv.w};
        float gaa[4] = {gav.x, gav.y, gav.z, gav.w};
        float res[4];
        #pragma unroll
        for (int q = 0; q < 4; ++q) {
            float v = xa[q] + hist[q] + elu1(sm[q]);
            res[q] = fmaf(gaa[q], bgv[kb], 1.0f) * (elu1(v) + 1.0f);
        }
        *reinterpret_cast<float4*>(out + (size_t)b * Nn + nq) =
            make_float4(res[0], res[1], res[2], res[3]);

        xv = xnext;
    }
}

extern "C" void kernel_launch(void* const* d_in, const int* in_sizes, int n_in,
                              void* d_out, int out_size, void* d_ws, size_t ws_size,
                              hipStream_t stream) {
    const float* x        = (const float*)d_in[0];
    const float* history  = (const float*)d_in[1];
    // d_in[2] = gain (unused)
    const float* state    = (const float*)d_in[3];
    const int*   sort_id  = (const int*)d_in[4];
    const float* hw       = (const float*)d_in[5];
    const float* hb       = (const float*)d_in[6];
    const float* sW       = (const float*)d_in[7];
    const float* sb       = (const float*)d_in[8];
    const float* own_gain = (const float*)d_in[9];
    const float* ga       = (const float*)d_in[10];
    float* out = (float*)d_out;

    const int nblocks = TILES * (Bsz / KB);   // 8 * 64 = 512 -> 2 blocks/CU exact
    main_kernel<<<nblocks, NT, 0, stream>>>(x, history, state, hw, hb, sW, sb,
                                            ga, sort_id, own_gain, out);
}